// Round 4
// baseline (536.970 us; speedup 1.0000x reference)
//
#include <hip/hip_runtime.h>
#include <hip/hip_bf16.h>
#include <stdint.h>

#define HH 768
#define WW 768
#define NN 200000
#define CI 256
#define CB 64

typedef __attribute__((ext_vector_type(8))) __bf16 bf16x8;
typedef __attribute__((ext_vector_type(4))) float f32x4;

__device__ inline unsigned short f2bf(float f) {
    union { float f; unsigned int i; } v; v.f = f;
    unsigned int r = v.i + 0x7FFF + ((v.i >> 16) & 1);
    return (unsigned short)(r >> 16);
}
__device__ inline f32x4 mfma16(bf16x8 a, bf16x8 b, f32x4 c) {
    return __builtin_amdgcn_mfma_f32_16x16x32_bf16(a, b, c, 0, 0, 0);
}
__device__ inline bf16x8 ldfrag(const unsigned short* p) {
    return *(const bf16x8*)p;
}
__device__ inline bf16x8 ldfrag_f32(const float* p) {
    float4 f0 = *(const float4*)(p);
    float4 f1 = *(const float4*)(p + 4);
    bf16x8 a;
    a[0] = (__bf16)f0.x; a[1] = (__bf16)f0.y; a[2] = (__bf16)f0.z; a[3] = (__bf16)f0.w;
    a[4] = (__bf16)f1.x; a[5] = (__bf16)f1.y; a[6] = (__bf16)f1.z; a[7] = (__bf16)f1.w;
    return a;
}
// pack 4 f32 (scaled/biased/relu'd) -> 4 bf16 and store as 8B
__device__ inline void st_bf16x4(unsigned short* p, f32x4 acc, float4 sc, float4 bi) {
    float v0 = acc[0] * sc.x + bi.x; v0 = v0 > 0.f ? v0 : 0.f;
    float v1 = acc[1] * sc.y + bi.y; v1 = v1 > 0.f ? v1 : 0.f;
    float v2 = acc[2] * sc.z + bi.z; v2 = v2 > 0.f ? v2 : 0.f;
    float v3 = acc[3] * sc.w + bi.w; v3 = v3 > 0.f ? v3 : 0.f;
    union { unsigned short u[4]; uint2 v; } pk;
    pk.u[0] = f2bf(v0); pk.u[1] = f2bf(v1); pk.u[2] = f2bf(v2); pk.u[3] = f2bf(v3);
    *(uint2*)p = pk.v;
}

// ---------------- prep kernels ----------------

__global__ void k_scatter(const int* __restrict__ coords, int* __restrict__ idx_map) {
    int i = blockIdx.x * 256 + threadIdx.x;
    if (i < NN) idx_map[coords[i]] = i;
}

__global__ void k_prepw(const float* __restrict__ w1,
                        const float* __restrict__ w2,
                        const float* __restrict__ w3,
                        unsigned short* __restrict__ w1t,
                        unsigned short* __restrict__ w2t,
                        unsigned short* __restrict__ w3t) {
    int tid = blockIdx.x * 256 + threadIdx.x;
    int stride = gridDim.x * 256;
    for (int i = tid; i < CI * CB; i += stride) {      // w1 [256][64] -> w1t [64][256]
        int k = i / CB, n = i % CB;
        w1t[n * CI + k] = f2bf(w1[i]);
    }
    for (int i = tid; i < 9 * CB * CB; i += stride) {  // w2 [9][64][64] -> per-tap [n][k]
        int t = i / (CB * CB), rem = i % (CB * CB);
        int k = rem / CB, n = rem % CB;
        w2t[t * CB * CB + n * CB + k] = f2bf(w2[i]);
    }
    for (int i = tid; i < CB * CI; i += stride) {      // w3 [64][256] -> w3t [256][64]
        int k = i / CI, n = i % CI;
        w3t[n * CB + k] = f2bf(w3[i]);
    }
}

// ---------------- stage 1: out1 = relu((feats @ w1)*s1 + b1), N x 64 ----------------
// wave = 64 rows (4 m-tiles) x full N=64 (4 n-tiles), K=256.
// MFMA called as (weights, acts): lane holds out[row = mt*16 + (lane&15)][col = nt*16 + quad*4 + r]

__global__ __launch_bounds__(256, 2) void k_gemm1(const float* __restrict__ feats,
                                                  const unsigned short* __restrict__ w1t,
                                                  const float* __restrict__ s1,
                                                  const float* __restrict__ b1,
                                                  unsigned short* __restrict__ out1) {
    const int wave = threadIdx.x >> 6;
    const int lane = threadIdx.x & 63;
    const int m = lane & 15;
    const int quad = lane >> 4;
    const int gw = blockIdx.x * 4 + wave;
    if (gw >= NN / 64) return;
    const int row0 = gw * 64;

    f32x4 acc[4][4];   // [mt][nt]
#pragma unroll
    for (int mt = 0; mt < 4; ++mt)
#pragma unroll
        for (int nt = 0; nt < 4; ++nt) acc[mt][nt] = (f32x4){0.f, 0.f, 0.f, 0.f};

#pragma unroll
    for (int ks = 0; ks < 8; ++ks) {
        bf16x8 x[4];
#pragma unroll
        for (int mt = 0; mt < 4; ++mt)
            x[mt] = ldfrag_f32(feats + (size_t)(row0 + mt * 16 + m) * CI + quad * 8 + ks * 32);
#pragma unroll
        for (int nt = 0; nt < 4; ++nt) {
            bf16x8 w = ldfrag(w1t + (nt * 16 + m) * CI + quad * 8 + ks * 32);
#pragma unroll
            for (int mt = 0; mt < 4; ++mt)
                acc[mt][nt] = mfma16(w, x[mt], acc[mt][nt]);
        }
    }

#pragma unroll
    for (int nt = 0; nt < 4; ++nt) {
        int col = nt * 16 + quad * 4;
        float4 sc = *(const float4*)(s1 + col);
        float4 bi = *(const float4*)(b1 + col);
#pragma unroll
        for (int mt = 0; mt < 4; ++mt)
            st_bf16x4(out1 + (size_t)(row0 + mt * 16 + m) * CB + col, acc[mt][nt], sc, bi);
    }
}

// ---------------- stage 2: gathered 3x3 conv + bn2 + relu ----------------

__global__ __launch_bounds__(256, 2) void k_conv(const unsigned short* __restrict__ out1,
                                                 const unsigned short* __restrict__ w2t,
                                                 const int* __restrict__ coords,
                                                 const int* __restrict__ idx_map,
                                                 const float* __restrict__ s2,
                                                 const float* __restrict__ b2,
                                                 const unsigned short* __restrict__ zrow,
                                                 unsigned short* __restrict__ out2) {
    __shared__ int s_nbr[256 * 9];
    const int tid = threadIdx.x;
    const int grow = blockIdx.x * 256 + tid;
    if (grow < NN) {
        int c = coords[grow];
        int y = c / WW, x = c - y * WW;
#pragma unroll
        for (int t = 0; t < 9; ++t) {
            int dy = t / 3 - 1, dx = t % 3 - 1;
            int ny = y + dy, nx = x + dx;
            int r = -1;
            if (ny >= 0 && ny < HH && nx >= 0 && nx < WW) r = idx_map[ny * WW + nx];
            s_nbr[tid * 9 + t] = r;
        }
    } else {
#pragma unroll
        for (int t = 0; t < 9; ++t) s_nbr[tid * 9 + t] = -1;
    }
    __syncthreads();

    const int wave = tid >> 6;
    const int lane = tid & 63;
    const int m = lane & 15;
    const int quad = lane >> 4;
    const int row0 = blockIdx.x * 256 + wave * 64;
    if (row0 >= NN) return;

    f32x4 acc[4][4];   // [mt][nt]
#pragma unroll
    for (int mt = 0; mt < 4; ++mt)
#pragma unroll
        for (int nt = 0; nt < 4; ++nt) acc[mt][nt] = (f32x4){0.f, 0.f, 0.f, 0.f};

#pragma unroll
    for (int t = 0; t < 9; ++t) {
        bf16x8 x[4][2];
#pragma unroll
        for (int mt = 0; mt < 4; ++mt) {
            int r = s_nbr[(wave * 64 + mt * 16 + m) * 9 + t];
            const unsigned short* base = (r >= 0) ? (out1 + (size_t)r * CB) : zrow;
            x[mt][0] = ldfrag(base + quad * 8);
            x[mt][1] = ldfrag(base + quad * 8 + 32);
        }
#pragma unroll
        for (int ks = 0; ks < 2; ++ks)
#pragma unroll
            for (int nt = 0; nt < 4; ++nt) {
                bf16x8 w = ldfrag(w2t + t * CB * CB + (nt * 16 + m) * CB + quad * 8 + ks * 32);
#pragma unroll
                for (int mt = 0; mt < 4; ++mt)
                    acc[mt][nt] = mfma16(w, x[mt][ks], acc[mt][nt]);
            }
    }

#pragma unroll
    for (int nt = 0; nt < 4; ++nt) {
        int col = nt * 16 + quad * 4;
        float4 sc = *(const float4*)(s2 + col);
        float4 bi = *(const float4*)(b2 + col);
#pragma unroll
        for (int mt = 0; mt < 4; ++mt)
            st_bf16x4(out2 + (size_t)(row0 + mt * 16 + m) * CB + col, acc[mt][nt], sc, bi);
    }
}

// ---------------- stage 3: out = relu((out2 @ w3)*s3 + b3 + feats), N x 256 ----------------
// block = 64 rows x 256 cols; wave = 64 rows x 64-col strip, K=64. float4 residual + store.

__global__ __launch_bounds__(256, 2) void k_gemm3(const unsigned short* __restrict__ out2,
                                                  const unsigned short* __restrict__ w3t,
                                                  const float* __restrict__ s3,
                                                  const float* __restrict__ b3,
                                                  const float* __restrict__ feats,
                                                  float* __restrict__ out) {
    const int wave = threadIdx.x >> 6;
    const int lane = threadIdx.x & 63;
    const int m = lane & 15;
    const int quad = lane >> 4;
    const int row0 = blockIdx.x * 64;
    const int col0 = wave * 64;

    f32x4 acc[4][4];   // [mt][nt]
#pragma unroll
    for (int mt = 0; mt < 4; ++mt)
#pragma unroll
        for (int nt = 0; nt < 4; ++nt) acc[mt][nt] = (f32x4){0.f, 0.f, 0.f, 0.f};

    bf16x8 x[4][2];
#pragma unroll
    for (int mt = 0; mt < 4; ++mt) {
        const unsigned short* ap = out2 + (size_t)(row0 + mt * 16 + m) * CB + quad * 8;
        x[mt][0] = ldfrag(ap);
        x[mt][1] = ldfrag(ap + 32);
    }
#pragma unroll
    for (int ks = 0; ks < 2; ++ks)
#pragma unroll
        for (int nt = 0; nt < 4; ++nt) {
            bf16x8 w = ldfrag(w3t + (col0 + nt * 16 + m) * CB + quad * 8 + ks * 32);
#pragma unroll
            for (int mt = 0; mt < 4; ++mt)
                acc[mt][nt] = mfma16(w, x[mt][ks], acc[mt][nt]);
        }

#pragma unroll
    for (int nt = 0; nt < 4; ++nt) {
        int col = col0 + nt * 16 + quad * 4;
        float4 sc = *(const float4*)(s3 + col);
        float4 bi = *(const float4*)(b3 + col);
#pragma unroll
        for (int mt = 0; mt < 4; ++mt) {
            int orow = row0 + mt * 16 + m;
            float4 id = *(const float4*)(feats + (size_t)orow * CI + col);
            float4 o;
            o.x = acc[mt][nt][0] * sc.x + bi.x + id.x; o.x = o.x > 0.f ? o.x : 0.f;
            o.y = acc[mt][nt][1] * sc.y + bi.y + id.y; o.y = o.y > 0.f ? o.y : 0.f;
            o.z = acc[mt][nt][2] * sc.z + bi.z + id.z; o.z = o.z > 0.f ? o.z : 0.f;
            o.w = acc[mt][nt][3] * sc.w + bi.w + id.w; o.w = o.w > 0.f ? o.w : 0.f;
            *(float4*)(out + (size_t)orow * CI + col) = o;
        }
    }
}

// ---------------- launch ----------------

extern "C" void kernel_launch(void* const* d_in, const int* in_sizes, int n_in,
                              void* d_out, int out_size, void* d_ws, size_t ws_size,
                              hipStream_t stream) {
    const float* feats = (const float*)d_in[0];
    const int* coords = (const int*)d_in[1];
    const float* w1 = (const float*)d_in[2];
    const float* w2 = (const float*)d_in[3];
    const float* w3 = (const float*)d_in[4];
    const float* s1 = (const float*)d_in[5];
    const float* b1 = (const float*)d_in[6];
    const float* s2 = (const float*)d_in[7];
    const float* b2 = (const float*)d_in[8];
    const float* s3 = (const float*)d_in[9];
    const float* b3 = (const float*)d_in[10];
    float* out = (float*)d_out;

    char* ws = (char*)d_ws;
    int* idx_map        = (int*)(ws + 0);                       // 2,359,296
    unsigned short* w1t = (unsigned short*)(ws + 2359296);      // 32,768
    unsigned short* w2t = (unsigned short*)(ws + 2392064);      // 73,728
    unsigned short* w3t = (unsigned short*)(ws + 2465792);      // 32,768
    unsigned short* out1= (unsigned short*)(ws + 2498560);      // 25,600,000
    unsigned short* out2= (unsigned short*)(ws + 28098560);     // 25,600,000
    unsigned short* zrow= (unsigned short*)(ws + 53698560);     // 128 zero bytes
    // total: 53,698,688 bytes

    hipMemsetAsync(idx_map, 0xFF, (size_t)HH * WW * 4, stream);
    hipMemsetAsync(zrow, 0x00, 128, stream);
    k_scatter<<<(NN + 255) / 256, 256, 0, stream>>>(coords, idx_map);
    k_prepw<<<64, 256, 0, stream>>>(w1, w2, w3, w1t, w2t, w3t);
    k_gemm1<<<(NN / 64 + 3) / 4, 256, 0, stream>>>(feats, w1t, s1, b1, out1);
    k_conv<<<(NN + 255) / 256, 256, 0, stream>>>(out1, w2t, coords, idx_map, s2, b2, zrow, out2);
    k_gemm3<<<NN / 64, 256, 0, stream>>>(out2, w3t, s3, b3, feats, out);
}